// Round 3
// baseline (307.290 us; speedup 1.0000x reference)
//
#include <hip/hip_runtime.h>
#include <stdint.h>

#define NN 512
#define PAIR 128
#define SINGLE 256

#define GAINv 1.5927812698663017f
#define RS2 0.70710678118654752f

typedef unsigned int uint;
typedef unsigned short ushort;
typedef short bf16x8 __attribute__((ext_vector_type(8)));
typedef float f32x4 __attribute__((ext_vector_type(4)));

__device__ __forceinline__ ushort f2b(float f){
  union{float f;uint i;}v; v.f=f;
  uint x=v.i;
  return (ushort)((x + 0x7FFFu + ((x>>16)&1u))>>16);  // RNE, finite inputs only
}
__device__ __forceinline__ float b2f(ushort u){ union{uint i;float f;}v; v.i=((uint)u)<<16; return v.f; }
__device__ __forceinline__ float b2f_lo(uint u){ union{uint i;float f;}v; v.i=u<<16; return v.f; }
__device__ __forceinline__ float b2f_hi(uint u){ union{uint i;float f;}v; v.i=u&0xFFFF0000u; return v.f; }
__device__ __forceinline__ float tanh_fast(float x){
  float xc = fminf(fmaxf(x,-8.f),8.f);
  float e = __expf(2.f*xc);
  return (e-1.f)*__builtin_amdgcn_rcpf(e+1.f);
}
__device__ __forceinline__ void gload_lds16(const void* g, void* lds){
  __builtin_amdgcn_global_load_lds(
      (const __attribute__((address_space(1))) uint32_t*)g,
      (__attribute__((address_space(3))) uint32_t*)lds, 16, 0, 0);
}

// ---------------- k1: g1 spin-sums of h_one (f32, atomic) + W2^T -> bf16 ----------
__global__ __launch_bounds__(256) void k1_prep(const float* __restrict__ h_one,
                                               const float* __restrict__ w2,
                                               float* __restrict__ g1acc,
                                               ushort* __restrict__ wt)
{
  const int b = blockIdx.x, t = threadIdx.x;
  if(b < 8){
    const int rb = b*64;
    float s = 0.f;
    for(int i=0;i<64;i++) s += h_one[(size_t)(rb+i)*SINGLE + t];
    atomicAdd(&g1acc[(b>>2)*SINGLE + t], s);      // b 0..3 -> spin0, 4..7 -> spin1
  } else {
    const int bb = b-8;                            // 16 rows of W2 each
    for(int e=t; e<16*128; e+=256){
      int kl = e>>7, n = e&127;
      int k = bb*16 + kl;
      wt[n*128 + k] = f2b(w2[(size_t)k*128 + n]);  // wt[n][k] = bf16(W2[k][n])
    }
  }
}

// ---------------- k2_gterm: gterm[n] = (g1_mean concat) @ Wg (f32) ----------------
__global__ __launch_bounds__(256) void k2_gterm(const float* __restrict__ g1acc,
                                                const float* __restrict__ wg,
                                                float* __restrict__ gterm)
{
  const int t = threadIdx.x;
  const int fb = blockIdx.x*64;
  float s = 0.f;
  for(int f=fb; f<fb+64; f++)
    s += g1acc[f]*(1.f/256.f)*wg[(size_t)f*SINGLE + t];
  atomicAdd(&gterm[t], s);
}

// ---------------- k3: fused h_two GEMM (MFMA via bf16 cast) + residual + g2 -------
// tile: 32 i's x 4 j's = 128 flat rows x 128 cols, K=128 resident.
__global__ __launch_bounds__(256, 2) void k3_htwo(
    const float* __restrict__ h_two,
    const float* __restrict__ b2,
    const ushort* __restrict__ wt,
    float* __restrict__ g2acc,
    float* __restrict__ out_h2)
{
  __shared__ __align__(16) ushort At[128*128];   // bf16 tile [r][k], r = di*4+dj
  __shared__ __align__(16) ushort Wt[128*128];   // bf16 [n][k]
  const int tid  = threadIdx.x;
  const int wave = tid>>6, lane = tid&63;
  const int bi = blockIdx.x & 15, bj = blockIdx.x >> 4;
  const int i0 = bi*32, j0 = bj*4;

  // stage Wt (already bf16 in global) via async LDS DMA
  for(int t=0;t<8;t++){
    int q = wave*8+t;
    gload_lds16(wt + q*512 + lane*8, &Wt[q*512]);
  }
  // stage At: f32 global -> convert -> bf16 LDS
  #pragma unroll
  for(int rep=0; rep<16; rep++){
    int e = rep*1024 + tid*4;                 // flat elem in tile, e = di*512 + c
    int di = e>>9, c = e&511;
    float4 v = *(const float4*)(h_two + ((size_t)(i0+di)*NN + j0)*PAIR + c);
    ushort4 pk; pk.x=f2b(v.x); pk.y=f2b(v.y); pk.z=f2b(v.z); pk.w=f2b(v.w);
    *(ushort4*)(&At[e]) = pk;
  }
  __syncthreads();

  // g2 column sums over the 32 i's (from bf16 tile; error << tolerance)
  {
    const int dj = tid>>6, pp = tid&63;
    const uint* a32 = (const uint*)At;
    float s0=0.f, s1=0.f;
    #pragma unroll
    for(int di=0;di<32;di++){
      uint u = a32[(di*4+dj)*64 + pp];
      s0 += b2f_lo(u); s1 += b2f_hi(u);
    }
    const int spin = bi>>3;
    float* dst = g2acc + ((size_t)spin*NN + (j0+dj))*PAIR + pp*2;
    atomicAdd(dst, s0); atomicAdd(dst+1, s1);
  }

  // GEMM: D[n][m] via A-op=Wt frags, B-op=At frags (transposed-output trick)
  const int wm = wave&1, wn = wave>>1;           // 2x2 wave grid, 64x64 each
  const int lq = lane>>4, lr = lane&15;
  f32x4 acc[4][4];
  #pragma unroll
  for(int a=0;a<4;a++)
    #pragma unroll
    for(int b=0;b<4;b++) acc[a][b]=(f32x4){0.f,0.f,0.f,0.f};

  #pragma unroll
  for(int kk=0;kk<4;kk++){
    const int k0 = kk*32 + lq*8;
    bf16x8 af[4], bfr[4];
    #pragma unroll
    for(int nt=0;nt<4;nt++){
      int n = wn*64 + nt*16 + lr;
      af[nt] = *(const bf16x8*)(&Wt[n*128 + k0]);
    }
    #pragma unroll
    for(int mt=0;mt<4;mt++){
      int m = wm*64 + mt*16 + lr;
      bfr[mt] = *(const bf16x8*)(&At[m*128 + k0]);
    }
    #pragma unroll
    for(int mt=0;mt<4;mt++)
      #pragma unroll
      for(int nt=0;nt<4;nt++)
        acc[mt][nt] = __builtin_amdgcn_mfma_f32_16x16x32_bf16(af[nt], bfr[mt], acc[mt][nt], 0,0,0);
  }

  // epilogue: bias + tanh*gain + residual (f32 re-read, L2-hot) -> f32 store
  #pragma unroll
  for(int mt=0;mt<4;mt++){
    const int m = wm*64 + mt*16 + lr;            // flat tile row -> (di=m>>2, dj=m&3)
    const size_t base = ((size_t)(i0 + (m>>2))*NN + (j0 + (m&3)))*PAIR;
    #pragma unroll
    for(int nt=0;nt<4;nt++){
      const int nb = wn*64 + nt*16 + lq*4;       // output feature n = nb..nb+3
      float4 bb = *(const float4*)(b2 + nb);
      float4 rr = *(const float4*)(h_two + base + nb);
      float4 o;
      o.x = (rr.x + GAINv*tanh_fast(acc[mt][nt][0] + bb.x))*RS2;
      o.y = (rr.y + GAINv*tanh_fast(acc[mt][nt][1] + bb.y))*RS2;
      o.z = (rr.z + GAINv*tanh_fast(acc[mt][nt][2] + bb.z))*RS2;
      o.w = (rr.w + GAINv*tanh_fast(acc[mt][nt][3] + bb.w))*RS2;
      *(float4*)(out_h2 + base + nb) = o;
    }
  }
}

// ---------------- k4: h_one path — per-element f32 ---------------------------------
__global__ __launch_bounds__(256) void k4_hone(
    const float* __restrict__ h_one,
    const float* __restrict__ w1,
    const float* __restrict__ b1,
    const float* __restrict__ g2acc,
    const float* __restrict__ gterm,
    float* __restrict__ out_h1)
{
  __shared__ float onein[512];
  const int n   = threadIdx.x;   // 0..255 output feature
  const int row = blockIdx.x;    // 0..511
  onein[n] = h_one[(size_t)row*SINGLE + n];
  {
    int spin = n>>7, p = n&127;
    onein[256 + n] = g2acc[((size_t)spin*NN + row)*PAIR + p] * (1.f/256.f);
  }
  __syncthreads();
  float acc = 0.f;
  for(int f=0; f<512; f++)
    acc += onein[f] * w1[(size_t)f*SINGLE + n];
  float x = (acc + b1[n] + gterm[n]) * RS2;
  float o = (onein[n] + GAINv*tanh_fast(x)) * RS2;
  out_h1[(size_t)row*SINGLE + n] = o;
}

extern "C" void kernel_launch(void* const* d_in, const int* in_sizes, int n_in,
                              void* d_out, int out_size, void* d_ws, size_t ws_size,
                              hipStream_t stream)
{
  const float* h_one = (const float*)d_in[0];
  const float* h_two = (const float*)d_in[1];
  const float* W1    = (const float*)d_in[2];
  const float* b1    = (const float*)d_in[3];
  const float* Wg    = (const float*)d_in[4];
  const float* W2    = (const float*)d_in[5];
  const float* b2    = (const float*)d_in[6];

  float* wsf    = (float*)d_ws;
  float* g2acc  = wsf;                       // [2][512][128] f32 sums (atomic)
  float* g1acc  = wsf + 131072;              // [2][256] f32 sums (atomic)
  float* gterm  = wsf + 131584;              // [256] f32 (atomic)
  ushort* wt    = (ushort*)(wsf + 131840);   // W2^T bf16 [n][k], 16384 elems

  float* out_h1 = (float*)d_out;
  float* out_h2 = out_h1 + 131072;

  hipMemsetAsync(wsf, 0, (size_t)(131072+512+256)*sizeof(float), stream);
  k1_prep <<<16,   256, 0, stream>>>(h_one, W2, g1acc, wt);
  k2_gterm<<<8,    256, 0, stream>>>(g1acc, Wg, gterm);
  k3_htwo <<<2048, 256, 0, stream>>>(h_two, b2, wt, g2acc, out_h2);
  k4_hone <<<512,  256, 0, stream>>>(h_one, W1, b1, g2acc, gterm, out_h1);
}